// Round 1
// baseline (528.056 us; speedup 1.0000x reference)
//
#include <hip/hip_runtime.h>

#define NTOK 2048
#define CDIM 1024
#define NHEAD 16
#define HDIM 64
#define NFRM 8
#define FTOK 256
#define NEG_BIG (-1.0e30f)

// ---------------------------------------------------------------------------
// Tiled fp32 GEMM: out = A[M,K] @ B[K,Ncol] + bias[Ncol]
// mode 0: plain row-major store to out[M,Ncol]
// mode 1: qkv scatter — out laid out as [3][NHEAD][NTOK][HDIM]
// 64x64 block tile, 256 threads, 4x4 microtile, BK=16.
// ---------------------------------------------------------------------------
__global__ __launch_bounds__(256)
void gemm_bias_kernel(const float* __restrict__ A,
                      const float* __restrict__ B,
                      const float* __restrict__ bias,
                      float* __restrict__ out,
                      int M, int Ncol, int K, int mode)
{
    __shared__ float As[16][68];   // As[k][m], pad 68 keeps float4 align + 2-way-max bank conflict
    __shared__ float Bs[16][68];   // Bs[k][n]

    const int t  = threadIdx.x;
    const int tx = t & 15, ty = t >> 4;
    const int row0 = blockIdx.y * 64;
    const int col0 = blockIdx.x * 64;

    const int lm  = t >> 2;   // A row 0..63
    const int lf  = t & 3;    // A k-chunk float4 idx 0..3
    const int lbk = t >> 4;   // B k row 0..15
    const int lbf = t & 15;   // B col float4 idx 0..15

    float acc[4][4] = {};

    for (int k0 = 0; k0 < K; k0 += 16) {
        float4 a4 = *(const float4*)(A + (size_t)(row0 + lm) * K + k0 + lf * 4);
        float4 b4 = *(const float4*)(B + (size_t)(k0 + lbk) * Ncol + col0 + lbf * 4);
        __syncthreads();   // previous iteration's LDS reads done
        As[lf*4+0][lm] = a4.x;
        As[lf*4+1][lm] = a4.y;
        As[lf*4+2][lm] = a4.z;
        As[lf*4+3][lm] = a4.w;
        *(float4*)&Bs[lbk][lbf*4] = b4;
        __syncthreads();
#pragma unroll
        for (int kk = 0; kk < 16; ++kk) {
            float4 av = *(const float4*)&As[kk][ty*4];
            float4 bv = *(const float4*)&Bs[kk][tx*4];
            float a[4] = {av.x, av.y, av.z, av.w};
            float b[4] = {bv.x, bv.y, bv.z, bv.w};
#pragma unroll
            for (int i = 0; i < 4; ++i)
#pragma unroll
                for (int j = 0; j < 4; ++j)
                    acc[i][j] = fmaf(a[i], b[j], acc[i][j]);
        }
    }

    float4 bv4 = *(const float4*)(bias + col0 + tx * 4);
    float bb[4] = {bv4.x, bv4.y, bv4.z, bv4.w};

    if (mode == 0) {
#pragma unroll
        for (int i = 0; i < 4; ++i) {
            int row = row0 + ty * 4 + i;
            float4 o4 = { acc[i][0] + bb[0], acc[i][1] + bb[1],
                          acc[i][2] + bb[2], acc[i][3] + bb[3] };
            *(float4*)(out + (size_t)row * Ncol + col0 + tx * 4) = o4;
        }
    } else {
        // col0 is a multiple of 64, so part/head fixed per block, d = tx*4+j
        const int part = col0 >> 10;
        const int h    = (col0 >> 6) & 15;
        float* dst = out + ((size_t)part * NHEAD + h) * (NTOK * HDIM);
#pragma unroll
        for (int i = 0; i < 4; ++i) {
            int row = row0 + ty * 4 + i;
            float4 o4 = { acc[i][0] + bb[0], acc[i][1] + bb[1],
                          acc[i][2] + bb[2], acc[i][3] + bb[3] };
            *(float4*)(dst + (size_t)row * HDIM + tx * 4) = o4;
        }
    }
}

// ---------------------------------------------------------------------------
// Flash attention with frame-block sparsity + hub masking + frame bias.
// One block = one (head, 64-query tile). Frames are contiguous 256-token
// blocks, so each 64-query tile lives in exactly one frame.
// Online softmax state held redundantly in registers (all 16 lanes sharing a
// row group compute identical m/l via shfl_xor butterfly).
// ---------------------------------------------------------------------------
__global__ __launch_bounds__(256)
void attn_kernel(const float* __restrict__ qkv,   // [3][NHEAD][NTOK][HDIM]
                 const int* __restrict__ frame_ids,
                 const int* __restrict__ is_hub,
                 const int* __restrict__ adj,
                 const float* __restrict__ frame_bias,
                 float* __restrict__ attn_out)    // [NTOK][CDIM]
{
    __shared__ float QsT[HDIM][68];   // Q^T: [d][m]
    __shared__ float KP[HDIM][68];    // K^T: [d][n], reused as P: [m][n]
    __shared__ float Vs[64][68];      // V:   [n][d]
    __shared__ int   khub[64];

    const int t  = threadIdx.x;
    const int tx = t & 15, ty = t >> 4;
    const int h  = blockIdx.y;
    const int q0 = blockIdx.x * 64;

    const float* Qp = qkv + (size_t)h * (NTOK * HDIM);
    const float* Kp = qkv + (size_t)(NHEAD + h) * (NTOK * HDIM);
    const float* Vp = qkv + (size_t)(2 * NHEAD + h) * (NTOK * HDIM);

    // Load Q tile transposed into LDS
#pragma unroll
    for (int r = 0; r < 4; ++r) {
        int m = ty + 16 * r;
        float4 a4 = *(const float4*)(Qp + (size_t)(q0 + m) * HDIM + tx * 4);
        QsT[tx*4+0][m] = a4.x;
        QsT[tx*4+1][m] = a4.y;
        QsT[tx*4+2][m] = a4.z;
        QsT[tx*4+3][m] = a4.w;
    }

    const int fq = frame_ids[q0];
    int qh[4];
#pragma unroll
    for (int i = 0; i < 4; ++i) qh[i] = is_hub[q0 + ty * 4 + i];

    float mcur[4], lcur[4], o[4][4];
#pragma unroll
    for (int i = 0; i < 4; ++i) {
        mcur[i] = -3.0e38f;
        lcur[i] = 0.0f;
#pragma unroll
        for (int j = 0; j < 4; ++j) o[i][j] = 0.0f;
    }

    for (int fj = 0; fj < NFRM; ++fj) {
        if (!adj[fq * NFRM + fj]) continue;     // frame not visible: skip entirely
        const float fbias = frame_bias[fq * NFRM + fj];
        const bool  same  = (fj == fq);

        for (int kt = 0; kt < 4; ++kt) {
            const int k0 = fj * FTOK + kt * 64;
            __syncthreads();   // previous tile's PV reads of KP/Vs complete (also Q store on first pass)

            // Load K^T and V tiles
#pragma unroll
            for (int r = 0; r < 4; ++r) {
                int m = ty + 16 * r;
                float4 k4 = *(const float4*)(Kp + (size_t)(k0 + m) * HDIM + tx * 4);
                KP[tx*4+0][m] = k4.x;
                KP[tx*4+1][m] = k4.y;
                KP[tx*4+2][m] = k4.z;
                KP[tx*4+3][m] = k4.w;
                float4 v4 = *(const float4*)(Vp + (size_t)(k0 + m) * HDIM + tx * 4);
                *(float4*)&Vs[m][tx*4] = v4;
            }
            if (t < 64) khub[t] = is_hub[k0 + t];
            __syncthreads();

            // S = Q @ K^T  (64x64, 4x4 per thread)
            float s[4][4] = {};
#pragma unroll 8
            for (int d = 0; d < HDIM; ++d) {
                float4 av = *(const float4*)&QsT[d][ty*4];
                float4 bv = *(const float4*)&KP[d][tx*4];
                float a[4] = {av.x, av.y, av.z, av.w};
                float b[4] = {bv.x, bv.y, bv.z, bv.w};
#pragma unroll
                for (int i = 0; i < 4; ++i)
#pragma unroll
                    for (int j = 0; j < 4; ++j)
                        s[i][j] = fmaf(a[i], b[j], s[i][j]);
            }

            int kh[4];
#pragma unroll
            for (int j = 0; j < 4; ++j) kh[j] = khub[tx*4+j];

            // scale BEFORE score_mod; bias only on allowed; hub blocks cross-frame only
#pragma unroll
            for (int i = 0; i < 4; ++i)
#pragma unroll
                for (int j = 0; j < 4; ++j) {
                    bool allow = same || ((qh[i] == 0) && (kh[j] == 0));
                    s[i][j] = allow ? fmaf(s[i][j], 0.125f, fbias) : NEG_BIG;
                }

            // Online softmax update (per row; 16 lanes with same ty share rows)
            float p[4][4];
#pragma unroll
            for (int i = 0; i < 4; ++i) {
                float rm = fmaxf(fmaxf(s[i][0], s[i][1]), fmaxf(s[i][2], s[i][3]));
                rm = fmaxf(rm, __shfl_xor(rm, 1));
                rm = fmaxf(rm, __shfl_xor(rm, 2));
                rm = fmaxf(rm, __shfl_xor(rm, 4));
                rm = fmaxf(rm, __shfl_xor(rm, 8));
                float mnew  = fmaxf(mcur[i], rm);
                float alpha = __expf(mcur[i] - mnew);
                mcur[i] = mnew;
                float sum = 0.0f;
#pragma unroll
                for (int j = 0; j < 4; ++j) {
                    p[i][j] = __expf(s[i][j] - mnew);
                    sum += p[i][j];
                }
                sum += __shfl_xor(sum, 1);
                sum += __shfl_xor(sum, 2);
                sum += __shfl_xor(sum, 4);
                sum += __shfl_xor(sum, 8);
                lcur[i] = lcur[i] * alpha + sum;
#pragma unroll
                for (int j = 0; j < 4; ++j) o[i][j] *= alpha;
            }

            __syncthreads();   // all S-reads of KP (as K^T) done
#pragma unroll
            for (int i = 0; i < 4; ++i) {
                float4 p4 = {p[i][0], p[i][1], p[i][2], p[i][3]};
                *(float4*)&KP[ty*4+i][tx*4] = p4;   // KP now holds P[m][n]
            }
            __syncthreads();

            // O += P @ V
#pragma unroll 8
            for (int j = 0; j < 64; ++j) {
                float4 v4 = *(const float4*)&Vs[j][tx*4];
#pragma unroll
                for (int i = 0; i < 4; ++i) {
                    float pij = KP[ty*4+i][j];
                    o[i][0] = fmaf(pij, v4.x, o[i][0]);
                    o[i][1] = fmaf(pij, v4.y, o[i][1]);
                    o[i][2] = fmaf(pij, v4.z, o[i][2]);
                    o[i][3] = fmaf(pij, v4.w, o[i][3]);
                }
            }
        }
    }

    // epilogue: normalize and store as [n][h*64+d] (row-major N x C)
#pragma unroll
    for (int i = 0; i < 4; ++i) {
        int row = q0 + ty * 4 + i;
        float inv = 1.0f / lcur[i];
        float4 o4 = { o[i][0]*inv, o[i][1]*inv, o[i][2]*inv, o[i][3]*inv };
        *(float4*)(attn_out + (size_t)row * CDIM + h * HDIM + tx * 4) = o4;
    }
}

// ---------------------------------------------------------------------------
extern "C" void kernel_launch(void* const* d_in, const int* in_sizes, int n_in,
                              void* d_out, int out_size, void* d_ws, size_t ws_size,
                              hipStream_t stream)
{
    const float* x          = (const float*)d_in[0];
    const int*   frame_ids  = (const int*)d_in[1];
    const int*   is_hub     = (const int*)d_in[2];
    const int*   adj        = (const int*)d_in[3];
    const float* frame_bias = (const float*)d_in[4];
    const float* Wqkv       = (const float*)d_in[5];
    const float* bqkv       = (const float*)d_in[6];
    const float* Wproj      = (const float*)d_in[7];
    const float* bproj      = (const float*)d_in[8];
    float* out = (float*)d_out;

    // workspace: qkv [3][16][2048][64] (25.2 MB) + attn_out [2048][1024] (8.4 MB) = 32 MiB
    float* qkv  = (float*)d_ws;
    float* attn = qkv + (size_t)3 * NHEAD * NTOK * HDIM;

    dim3 blk(256);

    // 1) QKV projection, scattered into [3][H][N][D]
    gemm_bias_kernel<<<dim3((3 * CDIM) / 64, NTOK / 64), blk, 0, stream>>>(
        x, Wqkv, bqkv, qkv, NTOK, 3 * CDIM, CDIM, 1);

    // 2) frame-sparse flash attention -> [N][C]
    attn_kernel<<<dim3(NTOK / 64, NHEAD), blk, 0, stream>>>(
        qkv, frame_ids, is_hub, adj, frame_bias, attn);

    // 3) output projection
    gemm_bias_kernel<<<dim3(CDIM / 64, NTOK / 64), blk, 0, stream>>>(
        attn, Wproj, bproj, out, NTOK, CDIM, CDIM, 0);
}

// Round 3
// 191.401 us; speedup vs baseline: 2.7589x; 2.7589x over previous
//
#include <hip/hip_runtime.h>

#define NTOK 2048
#define CDIM 1024
#define NHEAD 16
#define HDIM 64
#define NFRM 8
#define FTOK 256

typedef unsigned short ushort;
typedef __attribute__((ext_vector_type(8))) short short8;     // 8 bf16 = 4 VGPRs (MFMA A/B frag)
typedef __attribute__((ext_vector_type(8))) ushort ushort8;
typedef __attribute__((ext_vector_type(4))) ushort ushort4v;
typedef __attribute__((ext_vector_type(4))) float floatx4;    // MFMA C/D frag

__device__ __forceinline__ ushort f2bf(float f) {
    unsigned int u = __float_as_uint(f);
    return (ushort)((u + 0x7fffu + ((u >> 16) & 1u)) >> 16);   // RNE
}

// async global->LDS, 16B per lane; LDS dest = wave-uniform base + lane*16
__device__ __forceinline__ void gload_lds16(const void* g, void* l) {
    __builtin_amdgcn_global_load_lds(
        (const __attribute__((address_space(1))) unsigned int*)(uintptr_t)g,
        (__attribute__((address_space(3))) unsigned int*)(unsigned int)(uintptr_t)l,
        16, 0, 0);
}

// ---------------------------------------------------------------------------
// x fp32 -> bf16 elementwise
// ---------------------------------------------------------------------------
__global__ __launch_bounds__(256)
void convx_kernel(const float* __restrict__ x, ushort* __restrict__ xb, int n4)
{
    int i = blockIdx.x * 256 + threadIdx.x;
    if (i < n4) {
        float4 f = ((const float4*)x)[i];
        ushort4v o = { f2bf(f.x), f2bf(f.y), f2bf(f.z), f2bf(f.w) };
        ((ushort4v*)xb)[i] = o;
    }
}

// ---------------------------------------------------------------------------
// W[K][N] fp32 -> WT[N][K] bf16   (64x64 LDS tile transpose)
// R2 bug fix: write phase must cover all 8 k-chunks (512 ushort8 stores,
// 256 threads -> 2 per thread), not 4.
// ---------------------------------------------------------------------------
__global__ __launch_bounds__(256)
void wtrans_kernel(const float* __restrict__ W, ushort* __restrict__ WT, int K, int N)
{
    __shared__ ushort LT[64][72];   // [n][k], 144B row stride = 9x16B (keeps b128 aligned)
    const int t = threadIdx.x;
    const int k0 = blockIdx.y * 64, n0 = blockIdx.x * 64;
    const int kr = t >> 4, nc = t & 15;
#pragma unroll
    for (int i = 0; i < 4; ++i) {
        int k = kr + i * 16;
        float4 w4 = *(const float4*)(W + (size_t)(k0 + k) * N + n0 + nc * 4);
        LT[nc*4+0][k] = f2bf(w4.x);
        LT[nc*4+1][k] = f2bf(w4.y);
        LT[nc*4+2][k] = f2bf(w4.z);
        LT[nc*4+3][k] = f2bf(w4.w);
    }
    __syncthreads();
    const int n = t >> 2;
#pragma unroll
    for (int half = 0; half < 2; ++half) {
        int kc = (t & 3) + 4 * half;            // 0..7 -> k chunks cover 0..63
        ushort8 v = *(const ushort8*)&LT[n][kc * 8];
        *(ushort8*)(WT + (size_t)(n0 + n) * K + k0 + kc * 8) = v;
    }
}

// ---------------------------------------------------------------------------
// v bf16 [H][N][D] -> vT bf16 [H][D][N]
// R2 bug fix: both phases must cover the full 64x64 tile (2 iters each).
// ---------------------------------------------------------------------------
__global__ __launch_bounds__(256)
void vtrans_kernel(const ushort* __restrict__ v, ushort* __restrict__ vT)
{
    __shared__ ushort LT[64][72];   // [d][tok]
    const int t = threadIdx.x, h = blockIdx.y, n0 = blockIdx.x * 64;
    {
        const int tok = t >> 2;
#pragma unroll
        for (int half = 0; half < 2; ++half) {
            int dc = (t & 3) + 4 * half;        // 0..7 -> d chunks cover 0..63
            ushort8 v8 = *(const ushort8*)(v + ((size_t)h * NTOK + n0 + tok) * HDIM + dc * 8);
#pragma unroll
            for (int j = 0; j < 8; ++j) LT[dc*8 + j][tok] = v8[j];
        }
    }
    __syncthreads();
    {
        const int d = t >> 2;
#pragma unroll
        for (int half = 0; half < 2; ++half) {
            int tc = (t & 3) + 4 * half;        // 0..7 -> tok chunks cover 0..63
            ushort8 o8 = *(const ushort8*)&LT[d][tc * 8];
            *(ushort8*)(vT + ((size_t)h * HDIM + d) * NTOK + n0 + tc * 8) = o8;
        }
    }
}

// ---------------------------------------------------------------------------
// bf16 MFMA GEMM: C = A[M,K] @ BT[N,K]^T + bias
// 128x128 tile, 4 waves (2x2), BK=32, global_load_lds staging (m97 structure)
// mode 0: fp32 store row-major [M][N]
// mode 1: bf16 scatter into [3][H][N][D]
// ---------------------------------------------------------------------------
__global__ __launch_bounds__(256)
void gemm_bt_kernel(const ushort* __restrict__ A, const ushort* __restrict__ BT,
                    const float* __restrict__ bias, void* __restrict__ out,
                    int M, int N, int K, int mode)
{
    __shared__ ushort As[128 * 32];
    __shared__ ushort Bs[128 * 32];

    const int t = threadIdx.x;
    const int wave = t >> 6, lane = t & 63;
    const int quad = lane >> 4, l15 = lane & 15;
    const int row0 = blockIdx.y * 128, col0 = blockIdx.x * 128;
    const int wm = (wave >> 1) * 64, wn = (wave & 1) * 64;

    const int sr = lane >> 2;         // row within a 16-row staging group
    const int sc = (lane & 3) * 8;    // ushort offset (16B chunks)

    floatx4 acc[4][4];
#pragma unroll
    for (int i = 0; i < 4; ++i)
#pragma unroll
        for (int j = 0; j < 4; ++j) acc[i][j] = (floatx4){0.f, 0.f, 0.f, 0.f};

    for (int k0 = 0; k0 < K; k0 += 32) {
        __syncthreads();   // all frag reads of previous tile done
        {
            const int r0 = wave * 32;
            gload_lds16(A  + (size_t)(row0 + r0      + sr) * K + k0 + sc, &As[ r0       * 32]);
            gload_lds16(A  + (size_t)(row0 + r0 + 16 + sr) * K + k0 + sc, &As[(r0 + 16) * 32]);
            gload_lds16(BT + (size_t)(col0 + r0      + sr) * K + k0 + sc, &Bs[ r0       * 32]);
            gload_lds16(BT + (size_t)(col0 + r0 + 16 + sr) * K + k0 + sc, &Bs[(r0 + 16) * 32]);
        }
        __syncthreads();   // staging complete (drains vmcnt)

        short8 af[4], bfr[4];
#pragma unroll
        for (int i = 0; i < 4; ++i)
            af[i] = *(const short8*)&As[(wm + i * 16 + l15) * 32 + quad * 8];
#pragma unroll
        for (int j = 0; j < 4; ++j)
            bfr[j] = *(const short8*)&Bs[(wn + j * 16 + l15) * 32 + quad * 8];
#pragma unroll
        for (int i = 0; i < 4; ++i)
#pragma unroll
            for (int j = 0; j < 4; ++j)
                acc[i][j] = __builtin_amdgcn_mfma_f32_16x16x32_bf16(af[i], bfr[j], acc[i][j], 0, 0, 0);
    }

    // epilogue: C/D layout col=l15 (n), row=quad*4+reg (m)
    if (mode == 0) {
        float* outf = (float*)out;
#pragma unroll
        for (int j = 0; j < 4; ++j) {
            int col = col0 + wn + j * 16 + l15;
            float bb = bias[col];
#pragma unroll
            for (int i = 0; i < 4; ++i) {
                int rowb = row0 + wm + i * 16 + quad * 4;
#pragma unroll
                for (int r = 0; r < 4; ++r)
                    outf[(size_t)(rowb + r) * N + col] = acc[i][j][r] + bb;
            }
        }
    } else {
        ushort* outb = (ushort*)out;
#pragma unroll
        for (int j = 0; j < 4; ++j) {
            int col = col0 + wn + j * 16 + l15;
            float bb = bias[col];
            int part = col >> 10, hh = (col >> 6) & 15, d = col & 63;
            ushort* dst = outb + ((size_t)(part * NHEAD + hh) * NTOK) * HDIM + d;
#pragma unroll
            for (int i = 0; i < 4; ++i) {
                int rowb = row0 + wm + i * 16 + quad * 4;
#pragma unroll
                for (int r = 0; r < 4; ++r)
                    dst[(size_t)(rowb + r) * HDIM] = f2bf(acc[i][j][r] + bb);
            }
        }
    }
}

// ---------------------------------------------------------------------------
// MFMA flash attention with frame-block sparsity + hub mask + frame bias.
// Block = (head, 64-query tile); 4 waves, wave w owns q rows [w*16, w*16+16).
// ---------------------------------------------------------------------------
__global__ __launch_bounds__(256)
void attn_mfma_kernel(const ushort* __restrict__ qkvb,   // [3][H][N][D] bf16
                      const ushort* __restrict__ vTb,    // [H][D][N] bf16
                      const int* __restrict__ frame_ids,
                      const int* __restrict__ is_hub,
                      const int* __restrict__ adj,
                      const float* __restrict__ frame_bias,
                      ushort* __restrict__ attnb)        // [N][C] bf16
{
    __shared__ ushort Qs[64 * 64];
    __shared__ ushort Ks[64 * 64];
    __shared__ ushort VTs[64 * 64];
    __shared__ ushort Ps[4][16 * 72];   // per-wave P strip, row stride 72 (144B = 9x16B)
    __shared__ int khubs[64];

    const int t = threadIdx.x;
    const int wave = t >> 6, lane = t & 63;
    const int quad = lane >> 4, l15 = lane & 15;
    const int h = blockIdx.y, q0 = blockIdx.x * 64;

    const ushort* Qg = qkvb + ((size_t)h * NTOK) * HDIM;
    const ushort* Kg = qkvb + ((size_t)(NHEAD + h) * NTOK) * HDIM;
    const ushort* Vg = vTb + ((size_t)h * HDIM) * NTOK;

    const int sr = lane >> 3;         // row within 8-row staging group (128B rows)
    const int sc = (lane & 7) * 8;    // ushort offset

    // stage Q once
    {
        const int r0 = wave * 16;
        gload_lds16(Qg + (size_t)(q0 + r0     + sr) * HDIM + sc, &Qs[ r0      * 64]);
        gload_lds16(Qg + (size_t)(q0 + r0 + 8 + sr) * HDIM + sc, &Qs[(r0 + 8) * 64]);
    }

    const int fq = frame_ids[q0];
    int qh[4];
#pragma unroll
    for (int r = 0; r < 4; ++r) qh[r] = is_hub[q0 + wave * 16 + quad * 4 + r];

    float mcur[4], lcur[4];
    floatx4 oacc[4];
#pragma unroll
    for (int r = 0; r < 4; ++r) { mcur[r] = -3.0e38f; lcur[r] = 0.0f; }
#pragma unroll
    for (int dt = 0; dt < 4; ++dt) oacc[dt] = (floatx4){0.f, 0.f, 0.f, 0.f};

    for (int fj = 0; fj < NFRM; ++fj) {
        if (!adj[fq * NFRM + fj]) continue;
        const float fb = frame_bias[fq * NFRM + fj];
        const bool same = (fj == fq);

        for (int kt = 0; kt < 4; ++kt) {
            const int k0 = fj * FTOK + kt * 64;
            __syncthreads();   // previous tile's frag reads done
            {
                const int r0 = wave * 16;
                gload_lds16(Kg + (size_t)(k0 + r0     + sr) * HDIM + sc, &Ks[ r0      * 64]);
                gload_lds16(Kg + (size_t)(k0 + r0 + 8 + sr) * HDIM + sc, &Ks[(r0 + 8) * 64]);
                gload_lds16(Vg + (size_t)(r0     + sr) * NTOK + k0 + sc, &VTs[ r0      * 64]);
                gload_lds16(Vg + (size_t)(r0 + 8 + sr) * NTOK + k0 + sc, &VTs[(r0 + 8) * 64]);
            }
            if (t < 64) khubs[t] = is_hub[k0 + t];
            __syncthreads();   // staging complete

            // S strip [16 q][64 keys] = Q @ K^T
            floatx4 s[4];
#pragma unroll
            for (int nt = 0; nt < 4; ++nt) s[nt] = (floatx4){0.f, 0.f, 0.f, 0.f};
            short8 aq0 = *(const short8*)&Qs[(wave * 16 + l15) * 64 + quad * 8];
            short8 aq1 = *(const short8*)&Qs[(wave * 16 + l15) * 64 + 32 + quad * 8];
#pragma unroll
            for (int nt = 0; nt < 4; ++nt) {
                short8 bk0 = *(const short8*)&Ks[(nt * 16 + l15) * 64 + quad * 8];
                short8 bk1 = *(const short8*)&Ks[(nt * 16 + l15) * 64 + 32 + quad * 8];
                s[nt] = __builtin_amdgcn_mfma_f32_16x16x32_bf16(aq0, bk0, s[nt], 0, 0, 0);
                s[nt] = __builtin_amdgcn_mfma_f32_16x16x32_bf16(aq1, bk1, s[nt], 0, 0, 0);
            }

            int kh[4];
#pragma unroll
            for (int nt = 0; nt < 4; ++nt) kh[nt] = khubs[nt * 16 + l15];

            // mask + scale + bias, online softmax (row = wave*16 + quad*4 + r)
            float alpha[4];
#pragma unroll
            for (int r = 0; r < 4; ++r) {
                float sv[4];
#pragma unroll
                for (int nt = 0; nt < 4; ++nt) {
                    bool allow = same || ((qh[r] == 0) && (kh[nt] == 0));
                    sv[nt] = allow ? fmaf(s[nt][r], 0.125f, fb) : -1.0e30f;
                }
                float rm = fmaxf(fmaxf(sv[0], sv[1]), fmaxf(sv[2], sv[3]));
                rm = fmaxf(rm, __shfl_xor(rm, 1));
                rm = fmaxf(rm, __shfl_xor(rm, 2));
                rm = fmaxf(rm, __shfl_xor(rm, 4));
                rm = fmaxf(rm, __shfl_xor(rm, 8));
                float mnew = fmaxf(mcur[r], rm);
                float a = __expf(mcur[r] - mnew);
                float p[4], sum = 0.0f;
#pragma unroll
                for (int nt = 0; nt < 4; ++nt) { p[nt] = __expf(sv[nt] - mnew); sum += p[nt]; }
                sum += __shfl_xor(sum, 1);
                sum += __shfl_xor(sum, 2);
                sum += __shfl_xor(sum, 4);
                sum += __shfl_xor(sum, 8);
                lcur[r] = lcur[r] * a + sum;
                mcur[r] = mnew;
                alpha[r] = a;
                // P -> LDS (C-layout -> row-major A-layout), bf16
#pragma unroll
                for (int nt = 0; nt < 4; ++nt)
                    Ps[wave][(quad * 4 + r) * 72 + nt * 16 + l15] = f2bf(p[nt]);
            }
#pragma unroll
            for (int dt = 0; dt < 4; ++dt)
#pragma unroll
                for (int r = 0; r < 4; ++r) oacc[dt][r] *= alpha[r];

            // O strip += P @ V   (wave-private Ps; compiler orders LDS w->r)
            short8 ap0 = *(const short8*)&Ps[wave][l15 * 72 + quad * 8];
            short8 ap1 = *(const short8*)&Ps[wave][l15 * 72 + 32 + quad * 8];
#pragma unroll
            for (int dt = 0; dt < 4; ++dt) {
                short8 bv0 = *(const short8*)&VTs[(dt * 16 + l15) * 64 + quad * 8];
                short8 bv1 = *(const short8*)&VTs[(dt * 16 + l15) * 64 + 32 + quad * 8];
                oacc[dt] = __builtin_amdgcn_mfma_f32_16x16x32_bf16(ap0, bv0, oacc[dt], 0, 0, 0);
                oacc[dt] = __builtin_amdgcn_mfma_f32_16x16x32_bf16(ap1, bv1, oacc[dt], 0, 0, 0);
            }
        }
    }

    // epilogue: attnb[row][h*64 + d] bf16
#pragma unroll
    for (int dt = 0; dt < 4; ++dt) {
        int col = h * HDIM + dt * 16 + l15;
#pragma unroll
        for (int r = 0; r < 4; ++r) {
            int row = q0 + wave * 16 + quad * 4 + r;
            attnb[(size_t)row * CDIM + col] = f2bf(oacc[dt][r] / lcur[r]);
        }
    }
}

// ---------------------------------------------------------------------------
extern "C" void kernel_launch(void* const* d_in, const int* in_sizes, int n_in,
                              void* d_out, int out_size, void* d_ws, size_t ws_size,
                              hipStream_t stream)
{
    const float* x          = (const float*)d_in[0];
    const int*   frame_ids  = (const int*)d_in[1];
    const int*   is_hub     = (const int*)d_in[2];
    const int*   adj        = (const int*)d_in[3];
    const float* frame_bias = (const float*)d_in[4];
    const float* Wqkv       = (const float*)d_in[5];
    const float* bqkv       = (const float*)d_in[6];
    const float* Wproj      = (const float*)d_in[7];
    const float* bproj      = (const float*)d_in[8];
    float* out = (float*)d_out;

    // workspace layout (ushort units) — 32 MiB total
    ushort* xb     = (ushort*)d_ws;            // 2048*1024        = 2,097,152
    ushort* wqkvT  = xb     + 2097152;         // 3072*1024        = 3,145,728
    ushort* wprojT = wqkvT  + 3145728;         // 1024*1024        = 1,048,576
    ushort* qkvb   = wprojT + 1048576;         // 3*16*2048*64     = 6,291,456
    ushort* vTb    = qkvb   + 6291456;         // 16*64*2048       = 2,097,152
    ushort* attnb  = vTb    + 2097152;         // 2048*1024        = 2,097,152

    dim3 blk(256);

    convx_kernel<<<dim3((NTOK * CDIM / 4 + 255) / 256), blk, 0, stream>>>(x, xb, NTOK * CDIM / 4);
    wtrans_kernel<<<dim3(3 * CDIM / 64, CDIM / 64), blk, 0, stream>>>(Wqkv, wqkvT, CDIM, 3 * CDIM);
    wtrans_kernel<<<dim3(CDIM / 64, CDIM / 64), blk, 0, stream>>>(Wproj, wprojT, CDIM, CDIM);

    // QKV: [2048,1024] @ [1024,3072] -> bf16 scatter [3][H][N][D]
    gemm_bt_kernel<<<dim3(3 * CDIM / 128, NTOK / 128), blk, 0, stream>>>(
        xb, wqkvT, bqkv, qkvb, NTOK, 3 * CDIM, CDIM, 1);

    vtrans_kernel<<<dim3(NTOK / 64, NHEAD), blk, 0, stream>>>(
        qkvb + (size_t)2 * NHEAD * NTOK * HDIM, vTb);

    attn_mfma_kernel<<<dim3(NTOK / 64, NHEAD), blk, 0, stream>>>(
        qkvb, vTb, frame_ids, is_hub, adj, frame_bias, attnb);

    // proj: [2048,1024] @ [1024,1024] -> fp32 d_out
    gemm_bt_kernel<<<dim3(CDIM / 128, NTOK / 128), blk, 0, stream>>>(
        attnb, wprojT, bproj, out, NTOK, CDIM, CDIM, 0);
}

// Round 4
// 173.692 us; speedup vs baseline: 3.0402x; 1.1020x over previous
//
#include <hip/hip_runtime.h>

#define NTOK 2048
#define CDIM 1024
#define NHEAD 16
#define HDIM 64
#define NFRM 8
#define FTOK 256

typedef unsigned short ushort;
typedef __attribute__((ext_vector_type(8))) short short8;     // 8 bf16 = 4 VGPRs (MFMA A/B frag)
typedef __attribute__((ext_vector_type(8))) ushort ushort8;
typedef __attribute__((ext_vector_type(4))) ushort ushort4v;
typedef __attribute__((ext_vector_type(4))) float floatx4;    // MFMA C/D frag

__device__ __forceinline__ ushort f2bf(float f) {
    unsigned int u = __float_as_uint(f);
    return (ushort)((u + 0x7fffu + ((u >> 16) & 1u)) >> 16);   // RNE
}

// async global->LDS, 16B per lane; LDS dest = wave-uniform base + lane*16
__device__ __forceinline__ void gload_lds16(const void* g, void* l) {
    __builtin_amdgcn_global_load_lds(
        (const __attribute__((address_space(1))) unsigned int*)(uintptr_t)g,
        (__attribute__((address_space(3))) unsigned int*)(unsigned int)(uintptr_t)l,
        16, 0, 0);
}

// ---------------------------------------------------------------------------
// x fp32 -> bf16 elementwise
// ---------------------------------------------------------------------------
__global__ __launch_bounds__(256)
void convx_kernel(const float* __restrict__ x, ushort* __restrict__ xb, int n4)
{
    int i = blockIdx.x * 256 + threadIdx.x;
    if (i < n4) {
        float4 f = ((const float4*)x)[i];
        ushort4v o = { f2bf(f.x), f2bf(f.y), f2bf(f.z), f2bf(f.w) };
        ((ushort4v*)xb)[i] = o;
    }
}

// ---------------------------------------------------------------------------
// W[K][N] fp32 -> WT[N][K] bf16   (64x64 LDS tile transpose)
// ---------------------------------------------------------------------------
__global__ __launch_bounds__(256)
void wtrans_kernel(const float* __restrict__ W, ushort* __restrict__ WT, int K, int N)
{
    __shared__ ushort LT[64][72];   // [n][k]
    const int t = threadIdx.x;
    const int k0 = blockIdx.y * 64, n0 = blockIdx.x * 64;
    const int kr = t >> 4, nc = t & 15;
#pragma unroll
    for (int i = 0; i < 4; ++i) {
        int k = kr + i * 16;
        float4 w4 = *(const float4*)(W + (size_t)(k0 + k) * N + n0 + nc * 4);
        LT[nc*4+0][k] = f2bf(w4.x);
        LT[nc*4+1][k] = f2bf(w4.y);
        LT[nc*4+2][k] = f2bf(w4.z);
        LT[nc*4+3][k] = f2bf(w4.w);
    }
    __syncthreads();
    const int n = t >> 2;
#pragma unroll
    for (int half = 0; half < 2; ++half) {
        int kc = (t & 3) + 4 * half;
        ushort8 v = *(const ushort8*)&LT[n][kc * 8];
        *(ushort8*)(WT + (size_t)(n0 + n) * K + k0 + kc * 8) = v;
    }
}

// ---------------------------------------------------------------------------
// v bf16 [H][N][D] -> vT bf16 [H][D][N]
// ---------------------------------------------------------------------------
__global__ __launch_bounds__(256)
void vtrans_kernel(const ushort* __restrict__ v, ushort* __restrict__ vT)
{
    __shared__ ushort LT[64][72];   // [d][tok]
    const int t = threadIdx.x, h = blockIdx.y, n0 = blockIdx.x * 64;
    {
        const int tok = t >> 2;
#pragma unroll
        for (int half = 0; half < 2; ++half) {
            int dc = (t & 3) + 4 * half;
            ushort8 v8 = *(const ushort8*)(v + ((size_t)h * NTOK + n0 + tok) * HDIM + dc * 8);
#pragma unroll
            for (int j = 0; j < 8; ++j) LT[dc*8 + j][tok] = v8[j];
        }
    }
    __syncthreads();
    {
        const int d = t >> 2;
#pragma unroll
        for (int half = 0; half < 2; ++half) {
            int tc = (t & 3) + 4 * half;
            ushort8 o8 = *(const ushort8*)&LT[d][tc * 8];
            *(ushort8*)(vT + ((size_t)h * HDIM + d) * NTOK + n0 + tc * 8) = o8;
        }
    }
}

// ---------------------------------------------------------------------------
// bf16 MFMA GEMM: C = A[M,K] @ BT[N,K]^T + bias
// 128x128 tile, 4 waves (2x2), BK=32, DOUBLE-BUFFERED global_load_lds staging:
// one barrier per K-step, prefetch issued right after the barrier so the next
// barrier's vmcnt(0) drain finds it ~1 compute-phase in flight.
// mode 0: fp32 store row-major [M][N];  mode 1: bf16 scatter into [3][H][N][D]
// ---------------------------------------------------------------------------
__global__ __launch_bounds__(256)
void gemm_bt_kernel(const ushort* __restrict__ A, const ushort* __restrict__ BT,
                    const float* __restrict__ bias, void* __restrict__ out,
                    int M, int N, int K, int mode)
{
    __shared__ ushort As[2][128 * 32];
    __shared__ ushort Bs[2][128 * 32];

    const int t = threadIdx.x;
    const int wave = t >> 6, lane = t & 63;
    const int quad = lane >> 4, l15 = lane & 15;
    const int row0 = blockIdx.y * 128, col0 = blockIdx.x * 128;
    const int wm = (wave >> 1) * 64, wn = (wave & 1) * 64;

    const int sr = lane >> 2;         // row within a 16-row staging group
    const int sc = (lane & 3) * 8;    // ushort offset (16B chunks)
    const int r0 = wave * 32;

    floatx4 acc[4][4];
#pragma unroll
    for (int i = 0; i < 4; ++i)
#pragma unroll
        for (int j = 0; j < 4; ++j) acc[i][j] = (floatx4){0.f, 0.f, 0.f, 0.f};

    // stage K-step 0 into buffer 0
    gload_lds16(A  + (size_t)(row0 + r0      + sr) * K + sc, &As[0][ r0       * 32]);
    gload_lds16(A  + (size_t)(row0 + r0 + 16 + sr) * K + sc, &As[0][(r0 + 16) * 32]);
    gload_lds16(BT + (size_t)(col0 + r0      + sr) * K + sc, &Bs[0][ r0       * 32]);
    gload_lds16(BT + (size_t)(col0 + r0 + 16 + sr) * K + sc, &Bs[0][(r0 + 16) * 32]);

    const int nk = K >> 5;
    for (int ki = 0; ki < nk; ++ki) {
        __syncthreads();   // buf[ki&1] staged; all waves done reading buf[(ki+1)&1]
        if (ki + 1 < nk) {
            const int kn = (ki + 1) << 5;
            const int b = (ki + 1) & 1;
            gload_lds16(A  + (size_t)(row0 + r0      + sr) * K + kn + sc, &As[b][ r0       * 32]);
            gload_lds16(A  + (size_t)(row0 + r0 + 16 + sr) * K + kn + sc, &As[b][(r0 + 16) * 32]);
            gload_lds16(BT + (size_t)(col0 + r0      + sr) * K + kn + sc, &Bs[b][ r0       * 32]);
            gload_lds16(BT + (size_t)(col0 + r0 + 16 + sr) * K + kn + sc, &Bs[b][(r0 + 16) * 32]);
        }
        const ushort* as = As[ki & 1];
        const ushort* bs = Bs[ki & 1];

        short8 af[4], bfr[4];
#pragma unroll
        for (int i = 0; i < 4; ++i)
            af[i] = *(const short8*)&as[(wm + i * 16 + l15) * 32 + quad * 8];
#pragma unroll
        for (int j = 0; j < 4; ++j)
            bfr[j] = *(const short8*)&bs[(wn + j * 16 + l15) * 32 + quad * 8];
#pragma unroll
        for (int i = 0; i < 4; ++i)
#pragma unroll
            for (int j = 0; j < 4; ++j)
                acc[i][j] = __builtin_amdgcn_mfma_f32_16x16x32_bf16(af[i], bfr[j], acc[i][j], 0, 0, 0);
    }

    // epilogue: C/D layout col=l15 (n), row=quad*4+reg (m)
    if (mode == 0) {
        float* outf = (float*)out;
#pragma unroll
        for (int j = 0; j < 4; ++j) {
            int col = col0 + wn + j * 16 + l15;
            float bb = bias[col];
#pragma unroll
            for (int i = 0; i < 4; ++i) {
                int rowb = row0 + wm + i * 16 + quad * 4;
#pragma unroll
                for (int r = 0; r < 4; ++r)
                    outf[(size_t)(rowb + r) * N + col] = acc[i][j][r] + bb;
            }
        }
    } else {
        ushort* outb = (ushort*)out;
#pragma unroll
        for (int j = 0; j < 4; ++j) {
            int col = col0 + wn + j * 16 + l15;
            float bb = bias[col];
            int part = col >> 10, hh = (col >> 6) & 15, d = col & 63;
            ushort* dst = outb + ((size_t)(part * NHEAD + hh) * NTOK) * HDIM + d;
#pragma unroll
            for (int i = 0; i < 4; ++i) {
                int rowb = row0 + wm + i * 16 + quad * 4;
#pragma unroll
                for (int r = 0; r < 4; ++r)
                    dst[(size_t)(rowb + r) * HDIM] = f2bf(acc[i][j][r] + bb);
            }
        }
    }
}

// ---------------------------------------------------------------------------
// MFMA flash attention, frame-block sparse, double-buffered K/V pipeline.
// Block = (head, 64-query tile); wave w owns q rows [w*16, w*16+16).
// Visible frames packed 3 bits each into vpack (no local-array scratch).
// ---------------------------------------------------------------------------
__global__ __launch_bounds__(256)
void attn_mfma_kernel(const ushort* __restrict__ qkvb,   // [3][H][N][D] bf16
                      const ushort* __restrict__ vTb,    // [H][D][N] bf16
                      const int* __restrict__ frame_ids,
                      const int* __restrict__ is_hub,
                      const int* __restrict__ adj,
                      const float* __restrict__ frame_bias,
                      ushort* __restrict__ attnb)        // [N][C] bf16
{
    __shared__ ushort Qs[64 * 64];
    __shared__ ushort Ks[2][64 * 64];
    __shared__ ushort VTs[2][64 * 64];
    __shared__ ushort Ps[4][16 * 72];   // per-wave P strip, row stride 72

    const int t = threadIdx.x;
    const int wave = t >> 6, lane = t & 63;
    const int quad = lane >> 4, l15 = lane & 15;
    const int h = blockIdx.y, q0 = blockIdx.x * 64;

    const ushort* Qg = qkvb + ((size_t)h * NTOK) * HDIM;
    const ushort* Kg = qkvb + ((size_t)(NHEAD + h) * NTOK) * HDIM;
    const ushort* Vg = vTb + ((size_t)h * HDIM) * NTOK;

    const int sr = lane >> 3;         // row within 8-row staging group (128B rows)
    const int sc = (lane & 7) * 8;    // ushort offset
    const int r0s = wave * 16;

    // packed visible-frame list (uniform)
    const int fq = frame_ids[q0];
    unsigned vpack = 0; int nv = 0;
#pragma unroll
    for (int f = 0; f < NFRM; ++f)
        if (adj[fq * NFRM + f]) { vpack |= (unsigned)f << (3 * nv); ++nv; }
    const int ntot = nv * 4;

    // stage Q + first K/V tile (buffer 0)
    {
        gload_lds16(Qg + (size_t)(q0 + r0s     + sr) * HDIM + sc, &Qs[ r0s      * 64]);
        gload_lds16(Qg + (size_t)(q0 + r0s + 8 + sr) * HDIM + sc, &Qs[(r0s + 8) * 64]);
        const int k0 = (int)(vpack & 7u) * FTOK;
        gload_lds16(Kg + (size_t)(k0 + r0s     + sr) * HDIM + sc, &Ks[0][ r0s      * 64]);
        gload_lds16(Kg + (size_t)(k0 + r0s + 8 + sr) * HDIM + sc, &Ks[0][(r0s + 8) * 64]);
        gload_lds16(Vg + (size_t)(r0s     + sr) * NTOK + k0 + sc, &VTs[0][ r0s      * 64]);
        gload_lds16(Vg + (size_t)(r0s + 8 + sr) * NTOK + k0 + sc, &VTs[0][(r0s + 8) * 64]);
    }

    int qh[4];
#pragma unroll
    for (int r = 0; r < 4; ++r) qh[r] = is_hub[q0 + wave * 16 + quad * 4 + r];

    float mcur[4], lcur[4];
    floatx4 oacc[4];
#pragma unroll
    for (int r = 0; r < 4; ++r) { mcur[r] = -3.0e38f; lcur[r] = 0.0f; }
#pragma unroll
    for (int dt = 0; dt < 4; ++dt) oacc[dt] = (floatx4){0.f, 0.f, 0.f, 0.f};

    short8 aq0, aq1;

    for (int vt = 0; vt < ntot; ++vt) {
        const int fj = (int)((vpack >> (3 * (vt >> 2))) & 7u);
        const int k0 = fj * FTOK + (vt & 3) * 64;

        __syncthreads();   // buf[vt&1] staged; all waves done with buf[(vt+1)&1]

        if (vt == 0) {     // uniform branch: hoist invariant Q fragments
            aq0 = *(const short8*)&Qs[(wave * 16 + l15) * 64 + quad * 8];
            aq1 = *(const short8*)&Qs[(wave * 16 + l15) * 64 + 32 + quad * 8];
        }
        if (vt + 1 < ntot) {   // prefetch next tile into the other buffer
            const int fn = (int)((vpack >> (3 * ((vt + 1) >> 2))) & 7u);
            const int kn = fn * FTOK + ((vt + 1) & 3) * 64;
            const int b = (vt + 1) & 1;
            gload_lds16(Kg + (size_t)(kn + r0s     + sr) * HDIM + sc, &Ks[b][ r0s      * 64]);
            gload_lds16(Kg + (size_t)(kn + r0s + 8 + sr) * HDIM + sc, &Ks[b][(r0s + 8) * 64]);
            gload_lds16(Vg + (size_t)(r0s     + sr) * NTOK + kn + sc, &VTs[b][ r0s      * 64]);
            gload_lds16(Vg + (size_t)(r0s + 8 + sr) * NTOK + kn + sc, &VTs[b][(r0s + 8) * 64]);
        }

        // hub flags direct from global (L1-resident broadcast)
        int kh[4];
#pragma unroll
        for (int nt = 0; nt < 4; ++nt) kh[nt] = is_hub[k0 + nt * 16 + l15];
        const float fb = frame_bias[fq * NFRM + fj];
        const bool same = (fj == fq);

        const ushort* ks = Ks[vt & 1];
        const ushort* vs = VTs[vt & 1];

        // S strip [16 q][64 keys] = Q @ K^T
        floatx4 s[4];
#pragma unroll
        for (int nt = 0; nt < 4; ++nt) s[nt] = (floatx4){0.f, 0.f, 0.f, 0.f};
#pragma unroll
        for (int nt = 0; nt < 4; ++nt) {
            short8 bk0 = *(const short8*)&ks[(nt * 16 + l15) * 64 + quad * 8];
            short8 bk1 = *(const short8*)&ks[(nt * 16 + l15) * 64 + 32 + quad * 8];
            s[nt] = __builtin_amdgcn_mfma_f32_16x16x32_bf16(aq0, bk0, s[nt], 0, 0, 0);
            s[nt] = __builtin_amdgcn_mfma_f32_16x16x32_bf16(aq1, bk1, s[nt], 0, 0, 0);
        }

        // mask + scale + bias, online softmax (row = wave*16 + quad*4 + r)
        float alpha[4];
#pragma unroll
        for (int r = 0; r < 4; ++r) {
            float sv[4];
#pragma unroll
            for (int nt = 0; nt < 4; ++nt) {
                bool allow = same || ((qh[r] == 0) && (kh[nt] == 0));
                sv[nt] = allow ? fmaf(s[nt][r], 0.125f, fb) : -1.0e30f;
            }
            float rm = fmaxf(fmaxf(sv[0], sv[1]), fmaxf(sv[2], sv[3]));
            rm = fmaxf(rm, __shfl_xor(rm, 1));
            rm = fmaxf(rm, __shfl_xor(rm, 2));
            rm = fmaxf(rm, __shfl_xor(rm, 4));
            rm = fmaxf(rm, __shfl_xor(rm, 8));
            float mnew = fmaxf(mcur[r], rm);
            float a = __expf(mcur[r] - mnew);
            float p[4], sum = 0.0f;
#pragma unroll
            for (int nt = 0; nt < 4; ++nt) { p[nt] = __expf(sv[nt] - mnew); sum += p[nt]; }
            sum += __shfl_xor(sum, 1);
            sum += __shfl_xor(sum, 2);
            sum += __shfl_xor(sum, 4);
            sum += __shfl_xor(sum, 8);
            lcur[r] = lcur[r] * a + sum;
            mcur[r] = mnew;
            alpha[r] = a;
#pragma unroll
            for (int nt = 0; nt < 4; ++nt)
                Ps[wave][(quad * 4 + r) * 72 + nt * 16 + l15] = f2bf(p[nt]);
        }
#pragma unroll
        for (int dt = 0; dt < 4; ++dt)
#pragma unroll
            for (int r = 0; r < 4; ++r) oacc[dt][r] *= alpha[r];

        // O strip += P @ V   (wave-private Ps)
        short8 ap0 = *(const short8*)&Ps[wave][l15 * 72 + quad * 8];
        short8 ap1 = *(const short8*)&Ps[wave][l15 * 72 + 32 + quad * 8];
#pragma unroll
        for (int dt = 0; dt < 4; ++dt) {
            short8 bv0 = *(const short8*)&vs[(dt * 16 + l15) * 64 + quad * 8];
            short8 bv1 = *(const short8*)&vs[(dt * 16 + l15) * 64 + 32 + quad * 8];
            oacc[dt] = __builtin_amdgcn_mfma_f32_16x16x32_bf16(ap0, bv0, oacc[dt], 0, 0, 0);
            oacc[dt] = __builtin_amdgcn_mfma_f32_16x16x32_bf16(ap1, bv1, oacc[dt], 0, 0, 0);
        }
    }

    // epilogue: attnb[row][h*64 + d] bf16
#pragma unroll
    for (int dt = 0; dt < 4; ++dt) {
        int col = h * HDIM + dt * 16 + l15;
#pragma unroll
        for (int r = 0; r < 4; ++r) {
            int row = q0 + wave * 16 + quad * 4 + r;
            attnb[(size_t)row * CDIM + col] = f2bf(oacc[dt][r] / lcur[r]);
        }
    }
}

// ---------------------------------------------------------------------------
extern "C" void kernel_launch(void* const* d_in, const int* in_sizes, int n_in,
                              void* d_out, int out_size, void* d_ws, size_t ws_size,
                              hipStream_t stream)
{
    const float* x          = (const float*)d_in[0];
    const int*   frame_ids  = (const int*)d_in[1];
    const int*   is_hub     = (const int*)d_in[2];
    const int*   adj        = (const int*)d_in[3];
    const float* frame_bias = (const float*)d_in[4];
    const float* Wqkv       = (const float*)d_in[5];
    const float* bqkv       = (const float*)d_in[6];
    const float* Wproj      = (const float*)d_in[7];
    const float* bproj      = (const float*)d_in[8];
    float* out = (float*)d_out;

    // workspace layout (ushort units) — 32 MiB total
    ushort* xb     = (ushort*)d_ws;            // 2048*1024
    ushort* wqkvT  = xb     + 2097152;         // 3072*1024
    ushort* wprojT = wqkvT  + 3145728;         // 1024*1024
    ushort* qkvb   = wprojT + 1048576;         // 3*16*2048*64
    ushort* vTb    = qkvb   + 6291456;         // 16*64*2048
    ushort* attnb  = vTb    + 2097152;         // 2048*1024

    dim3 blk(256);

    convx_kernel<<<dim3((NTOK * CDIM / 4 + 255) / 256), blk, 0, stream>>>(x, xb, NTOK * CDIM / 4);
    wtrans_kernel<<<dim3(3 * CDIM / 64, CDIM / 64), blk, 0, stream>>>(Wqkv, wqkvT, CDIM, 3 * CDIM);
    wtrans_kernel<<<dim3(CDIM / 64, CDIM / 64), blk, 0, stream>>>(Wproj, wprojT, CDIM, CDIM);

    // QKV: [2048,1024] @ [1024,3072] -> bf16 scatter [3][H][N][D]
    gemm_bt_kernel<<<dim3(3 * CDIM / 128, NTOK / 128), blk, 0, stream>>>(
        xb, wqkvT, bqkv, qkvb, NTOK, 3 * CDIM, CDIM, 1);

    vtrans_kernel<<<dim3(NTOK / 64, NHEAD), blk, 0, stream>>>(
        qkvb + (size_t)2 * NHEAD * NTOK * HDIM, vTb);

    attn_mfma_kernel<<<dim3(NTOK / 64, NHEAD), blk, 0, stream>>>(
        qkvb, vTb, frame_ids, is_hub, adj, frame_bias, attnb);

    // proj: [2048,1024] @ [1024,1024] -> fp32 d_out
    gemm_bt_kernel<<<dim3(CDIM / 128, NTOK / 128), blk, 0, stream>>>(
        attnb, wprojT, bproj, out, NTOK, CDIM, CDIM, 0);
}